// Round 4
// baseline (17.631 us; speedup 1.0000x reference)
//
#include <hip/hip_runtime.h>

#define CANVAS 28
#define TSTEPS 64
#define GCONST 196.0f   // (SIZE/2)^2

// out[b,i,j] = min(1, exp(P(i,j) + max_t [A_t + cx_t*rj + cy_t*ri]))
// A = ln(I) - g(x^2+y^2), cx = 2gx, cy = 2gy, P = -g(rj^2 + ri^2)
// Strokes processed in PAIRS: m = v_max3(m, s_t, s_{t+1}) -> 1.5 VALU/px/stroke.
__global__ __launch_bounds__(128) void draw_image_kernel(
    const float* __restrict__ x,   // (B, 64, 3)
    float* __restrict__ out)       // (B, 28, 28)
{
    const int b    = blockIdx.x;
    const int tid  = threadIdx.x;   // 0..127
    const int wave = tid >> 6;      // 0,1: rows 14*wave .. 14*wave+13
    const int lane = tid & 63;

    // lane t owns stroke t's coefficients in VGPRs
    const float xv = x[b * 192 + lane * 3 + 0];
    const float yv = x[b * 192 + lane * 3 + 1];
    const float iv = x[b * 192 + lane * 3 + 2];
    const float vA  = __logf(iv) - GCONST * (xv * xv + yv * yv);  // -inf ok
    const float vCx = 2.0f * GCONST * xv;
    const float vCy = 2.0f * GCONST * yv;

    // lane (<56) -> row = 14*wave + lane/4, cols 7*(lane%4)..+6
    const int lrow = lane >> 2;
    const int lcg  = lane & 3;
    const bool active = (lrow < 14);
    const int row = 14 * wave + (active ? lrow : 0);
    const float ri = (float)row * (1.0f / CANVAS) - 0.5f;

    float rj[7];
    #pragma unroll
    for (int k = 0; k < 7; ++k)
        rj[k] = (float)(lcg * 7 + k) * (1.0f / CANVAS) - 0.5f;

    float m[7];
    #pragma unroll
    for (int k = 0; k < 7; ++k) m[k] = -1e30f;

    #pragma unroll
    for (int t = 0; t < TSTEPS; t += 2) {
        const float A0  = __builtin_bit_cast(float,
            __builtin_amdgcn_readlane(__builtin_bit_cast(int, vA),  t));
        const float cx0 = __builtin_bit_cast(float,
            __builtin_amdgcn_readlane(__builtin_bit_cast(int, vCx), t));
        const float cy0 = __builtin_bit_cast(float,
            __builtin_amdgcn_readlane(__builtin_bit_cast(int, vCy), t));
        const float A1  = __builtin_bit_cast(float,
            __builtin_amdgcn_readlane(__builtin_bit_cast(int, vA),  t + 1));
        const float cx1 = __builtin_bit_cast(float,
            __builtin_amdgcn_readlane(__builtin_bit_cast(int, vCx), t + 1));
        const float cy1 = __builtin_bit_cast(float,
            __builtin_amdgcn_readlane(__builtin_bit_cast(int, vCy), t + 1));
        const float h0 = __builtin_fmaf(cy0, ri, A0);
        const float h1 = __builtin_fmaf(cy1, ri, A1);
        #pragma unroll
        for (int k = 0; k < 7; ++k) {
            const float s0 = __builtin_fmaf(cx0, rj[k], h0);
            const float s1 = __builtin_fmaf(cx1, rj[k], h1);
            float d;
            asm("v_max3_f32 %0, %1, %2, %3"
                : "=v"(d) : "v"(m[k]), "v"(s0), "v"(s1));
            m[k] = d;
        }
    }

    if (active) {
        const float pc = -GCONST * ri * ri;
        float* outp = out + b * (CANVAS * CANVAS) + row * CANVAS + lcg * 7;
        #pragma unroll
        for (int k = 0; k < 7; ++k) {
            const float p = __builtin_fmaf(-GCONST, rj[k] * rj[k], pc);
            outp[k] = fminf(__expf(m[k] + p), 1.0f);
        }
    }
}

extern "C" void kernel_launch(void* const* d_in, const int* in_sizes, int n_in,
                              void* d_out, int out_size, void* d_ws, size_t ws_size,
                              hipStream_t stream) {
    const float* x = (const float*)d_in[0];
    float* out = (float*)d_out;
    const int B = in_sizes[0] / (TSTEPS * 3);   // 1024
    draw_image_kernel<<<dim3(B), dim3(128), 0, stream>>>(x, out);
}

// Round 5
// 12.463 us; speedup vs baseline: 1.4147x; 1.4147x over previous
//
#include <hip/hip_runtime.h>

#define CANVAS 28
#define TSTEPS 64
#define GCONST 196.0f   // (SIZE/2)^2

// out[b,i,j] = min(1, max_t inten*exp(-g(rj-x)^2)*exp(-g(ri-y)^2))
//            = min(1, exp(P(i,j) + max_t [A_t + cx_t*rj + cy_t*ri]))
// A = ln(I) - g(x^2+y^2), cx = 2gx, cy = 2gy, P = -g(rj^2 + ri^2)
__global__ __launch_bounds__(256) void draw_image_kernel(
    const float* __restrict__ x,   // (B, 64, 3)
    float* __restrict__ out)       // (B, 28, 28)
{
    const int b   = blockIdx.x;
    const int tid = threadIdx.x;

    __shared__ float4 s_abc[TSTEPS];   // {A, cx, cy, _} per stroke

    if (tid < TSTEPS) {
        const float xv = x[b * (TSTEPS * 3) + tid * 3 + 0];
        const float yv = x[b * (TSTEPS * 3) + tid * 3 + 1];
        const float iv = x[b * (TSTEPS * 3) + tid * 3 + 2];
        const float li = __logf(iv);   // -inf for iv==0: flows correctly through fmax
        s_abc[tid] = make_float4(li - GCONST * (xv * xv + yv * yv),
                                 2.0f * GCONST * xv,
                                 2.0f * GCONST * yv, 0.0f);
    }
    __syncthreads();

    // 196 threads: each owns a 1x4 tile (row = tid/7, cols = (tid%7)*4 .. +3)
    if (tid < 196) {
        const int row = tid / 7;
        const int cg  = tid - row * 7;
        const float ri = (float)row * (1.0f / CANVAS) - 0.5f;
        float rj[4];
        #pragma unroll
        for (int k = 0; k < 4; ++k)
            rj[k] = (float)(cg * 4 + k) * (1.0f / CANVAS) - 0.5f;

        float m0 = -1e30f, m1 = -1e30f, m2 = -1e30f, m3 = -1e30f;

        #pragma unroll 8
        for (int t = 0; t < TSTEPS; ++t) {
            const float4 abc = s_abc[t];                       // broadcast b128
            const float h = __builtin_fmaf(abc.z, ri, abc.x);  // A + cy*ri
            m0 = fmaxf(m0, __builtin_fmaf(abc.y, rj[0], h));
            m1 = fmaxf(m1, __builtin_fmaf(abc.y, rj[1], h));
            m2 = fmaxf(m2, __builtin_fmaf(abc.y, rj[2], h));
            m3 = fmaxf(m3, __builtin_fmaf(abc.y, rj[3], h));
        }

        const float pc = -GCONST * ri * ri;
        float4 o;
        o.x = fminf(__expf(m0 + __builtin_fmaf(-GCONST, rj[0] * rj[0], pc)), 1.0f);
        o.y = fminf(__expf(m1 + __builtin_fmaf(-GCONST, rj[1] * rj[1], pc)), 1.0f);
        o.z = fminf(__expf(m2 + __builtin_fmaf(-GCONST, rj[2] * rj[2], pc)), 1.0f);
        o.w = fminf(__expf(m3 + __builtin_fmaf(-GCONST, rj[3] * rj[3], pc)), 1.0f);

        float* outp = out + b * (CANVAS * CANVAS) + row * CANVAS + cg * 4;
        *reinterpret_cast<float4*>(outp) = o;   // 16B aligned: 784,112,16 all %16==0
    }
}

extern "C" void kernel_launch(void* const* d_in, const int* in_sizes, int n_in,
                              void* d_out, int out_size, void* d_ws, size_t ws_size,
                              hipStream_t stream) {
    const float* x = (const float*)d_in[0];
    float* out = (float*)d_out;
    const int B = in_sizes[0] / (TSTEPS * 3);   // 1024
    draw_image_kernel<<<dim3(B), dim3(256), 0, stream>>>(x, out);
}